// Round 8
// baseline (1781.692 us; speedup 1.0000x reference)
//
#include <hip/hip_runtime.h>
#include <math.h>

#define SEQ   2048
#define BATCH 128
#define HID   256
#define VST   20   // v chunk stride in floats (80B): 16 chunk bases -> 8 bank
                   // quads x 2 addrs = 2-way max on b128 reads (free, m136)

// Cross-lane helpers (validated round 6).
// 0xB1 = quad_perm xor1; 0x4E = quad_perm xor2; 0x128 = row_ror:8 == xor8
// within 16-lane rows. ds_swizzle BitMode: 0x101F = xor4, 0x401F = xor16.
template <int CTRL>
__device__ __forceinline__ float dpp_mov(float x) {
    return __int_as_float(__builtin_amdgcn_update_dpp(
        __float_as_int(x), __float_as_int(x), CTRL, 0xF, 0xF, false));
}
template <int PAT>
__device__ __forceinline__ float swz(float x) {
    return __int_as_float(__builtin_amdgcn_ds_swizzle(__float_as_int(x), PAT));
}
// Zero-instruction arch-VGPR anchor: "+v" forces each component into an
// architected VGPR at this program point. Placed inside the t-loop so the RA
// cannot exile the weights to AGPRs (round 6: VGPR=108 + ~150 AGPR meant a
// v_accvgpr_read per weight use -> 2x VALU instrs, the 1466 cyc/step cause).
#define PIN4(v) asm volatile("" : "+v"((v).x), "+v"((v).y), "+v"((v).z), "+v"((v).w))

// One block (512 threads, 8 waves, 2 waves/EU) per batch element. fp32.
// Thread (R=tid>>4, l=tid&15): k-chunk [16l,16l+16), rows 8R+((tid&7)^j)
// XOR-ordered -> 128 weight fp32 pinned in arch VGPRs. Reduce = DPP/swizzle
// butterfly (validated round 6): thread tid ends with the full dot of row
// 8R+(tid&7), duplicated bit-identically in tid^8.
// Head is FUSED: yc = (tid&8)==0 ? h*W0[row] : 0, 5-round 32-lane butterfly,
// lanes (tid&31)==0 write 16 partials to double-buffered ypart; thread 0 sums
// the PREVIOUS step's buffer after the existing barrier (no extra barrier,
// no race: read buffer != write buffer). Removes the 190us head kernel.
// NOTE round-7 compile fail: LDS pointers must NOT go through pointer-array
// initializers (addrspacecast static init rejected) — pass as lambda args in
// an unrolled-x2 loop instead (round-6 structure).
__global__ __launch_bounds__(512) __attribute__((amdgpu_waves_per_eu(2, 2)))
void rnn_scan_kernel(const float* __restrict__ x,        // (SEQ, BATCH)
                     const float* __restrict__ h0,       // (BATCH, HID)
                     const float* __restrict__ W_ih,     // (HID, 1)
                     const float* __restrict__ W_hh,     // (HID, HID)
                     const float* __restrict__ W_hh_b,   // (HID, HID)
                     const float* __restrict__ b_h,      // (HID,)
                     const float* __restrict__ W,        // (OUT, HID)
                     const float* __restrict__ bias,     // (OUT,)
                     const int*   __restrict__ context,  // scalar
                     float*       __restrict__ y,        // (BATCH, SEQ)
                     float*       __restrict__ out_hs)   // (BATCH, SEQ, HID)
{
    const int b   = blockIdx.x;
    const int tid = threadIdx.x;
    const int R   = tid >> 4;    // row-group: rows [8R, 8R+8)
    const int l   = tid & 15;    // k-chunk index
    const int l7  = tid & 7;
    const int row = 8 * R + l7;  // row this thread owns after the reduce

    __shared__ __align__(16) float v_lds[2][16 * VST];
    __shared__ __align__(16) float ypart[2][16];
    __shared__ float x_lds[SEQ];

    for (int t = tid; t < SEQ; t += 512)
        x_lds[t] = x[t * BATCH + b];

    const float ctx = (float)context[0];

    // wreg[j][c] = W_eff[8R + (l7^j)][16l + 4c .. +3]  (XOR-ordered rows)
    float4 wreg[8][4];
    #pragma unroll
    for (int j = 0; j < 8; ++j) {
        const int rj = 8 * R + (l7 ^ j);
        const float* wp = W_hh   + (size_t)rj * HID + 16 * l;
        const float* bp = W_hh_b + (size_t)rj * HID + 16 * l;
        #pragma unroll
        for (int c = 0; c < 4; ++c) {
            const float4 a = *(const float4*)(wp + 4 * c);
            const float4 d = *(const float4*)(bp + 4 * c);
            wreg[j][c] = make_float4(a.x + ctx * d.x, a.y + ctx * d.y,
                                     a.z + ctx * d.z, a.w + ctx * d.w);
        }
    }

    const float winj = W_ih[row];
    const float bhj  = b_h[row];
    const float w0r  = W[row];       // head weight for this row
    const float b0   = bias[0];

    const int voff = VST * (row >> 4) + (row & 15);
    v_lds[0][voff] = 2.f * h0[(size_t)b * HID + row] - 1.f;  // dup-safe

    float* outp = out_hs + (size_t)b * SEQ * HID + row;
    float* yp   = y + (size_t)b * SEQ;

    const float4* vr0 = (const float4*)(v_lds[0] + VST * l);  // 80B-stride
    const float4* vr1 = (const float4*)(v_lds[1] + VST * l);

    __syncthreads();  // v[0] + x_lds ready

    auto step = [&](int t, const float4* __restrict__ vr,
                    float* __restrict__ vw,
                    const float* __restrict__ ypr,     // ypart of step t-1
                    float* __restrict__ ypw) {         // ypart of step t
        // Re-anchor the weights in arch VGPRs every iteration (no-op insts).
        #pragma unroll
        for (int j = 0; j < 8; ++j) {
            PIN4(wreg[j][0]); PIN4(wreg[j][1]);
            PIN4(wreg[j][2]); PIN4(wreg[j][3]);
        }

        // Head result for step t-1 (partials written before the last barrier,
        // into the other ypart buffer than this step writes).
        if (tid == 0 && t > 0) {
            const float4 s0 = *(const float4*)(ypr + 0);
            const float4 s1 = *(const float4*)(ypr + 4);
            const float4 s2 = *(const float4*)(ypr + 8);
            const float4 s3 = *(const float4*)(ypr + 12);
            yp[t - 1] = b0 + (((s0.x + s0.y) + (s0.z + s0.w)) +
                              ((s1.x + s1.y) + (s1.z + s1.w))) +
                             (((s2.x + s2.y) + (s2.z + s2.w)) +
                              ((s3.x + s3.y) + (s3.z + s3.w)));
        }

        float q[8] = {0.f, 0.f, 0.f, 0.f, 0.f, 0.f, 0.f, 0.f};
        #pragma unroll
        for (int c = 0; c < 4; ++c) {
            const float4 v4 = vr[c];
            #pragma unroll
            for (int j = 0; j < 8; ++j) {
                const float4 w = wreg[j][c];
                q[j] += w.x * v4.x;
                q[j] += w.y * v4.y;
                q[j] += w.z * v4.z;
                q[j] += w.w * v4.w;
            }
        }
        // Fold l <-> l^8 (same rows, complementary k-halves), then XOR
        // transpose small-mask-first; only xor4 touches the LDS pipe.
        #pragma unroll
        for (int j = 0; j < 8; ++j) q[j] += dpp_mov<0x128>(q[j]);
        q[0] += dpp_mov<0xB1>(q[1]);
        q[2] += dpp_mov<0xB1>(q[3]);
        q[4] += dpp_mov<0xB1>(q[5]);
        q[6] += dpp_mov<0xB1>(q[7]);
        q[0] += dpp_mov<0x4E>(q[2]);
        q[4] += dpp_mov<0x4E>(q[6]);
        q[0] += swz<0x101F>(q[4]);
        // q[0] = full dot for row 8R+l7 (bit-identical dup in tid^8)

        const float pre = q[0] + bhj + x_lds[t] * winj;
        const float h = 1.f / (1.f + __expf(-pre));

        // Fused head: each row contributes once (dup thread zeroed).
        float yc = ((tid & 8) == 0) ? h * w0r : 0.f;
        yc += dpp_mov<0xB1>(yc);
        yc += dpp_mov<0x4E>(yc);
        yc += swz<0x101F>(yc);
        yc += dpp_mov<0x128>(yc);
        yc += swz<0x401F>(yc);          // all lanes hold their 32-group sum
        if ((tid & 31) == 0) ypw[tid >> 5] = yc;

        vw[voff] = 2.f * h - 1.f;       // dup write, same value: benign
        if ((tid & 8) == 0)
            outp[(size_t)t * HID] = h;  // coalesced store, rows 32w..+32

        __syncthreads();  // v[t+1] + ypart[t] ready; buffer fully read
    };

    for (int t = 0; t < SEQ; t += 2) {
        step(t,     vr0, v_lds[1], ypart[1], ypart[0]);
        step(t + 1, vr1, v_lds[0], ypart[0], ypart[1]);
    }

    if (tid == 0) {   // head result for the final step (SEQ-1 odd -> ypart[1])
        const float* pp = ypart[(SEQ - 1) & 1];
        const float4 s0 = *(const float4*)(pp + 0);
        const float4 s1 = *(const float4*)(pp + 4);
        const float4 s2 = *(const float4*)(pp + 8);
        const float4 s3 = *(const float4*)(pp + 12);
        yp[SEQ - 1] = b0 + (((s0.x + s0.y) + (s0.z + s0.w)) +
                            ((s1.x + s1.y) + (s1.z + s1.w))) +
                           (((s2.x + s2.y) + (s2.z + s2.w)) +
                            ((s3.x + s3.y) + (s3.z + s3.w)));
    }
}

extern "C" void kernel_launch(void* const* d_in, const int* in_sizes, int n_in,
                              void* d_out, int out_size, void* d_ws, size_t ws_size,
                              hipStream_t stream) {
    const float* x      = (const float*)d_in[0];
    const float* h0     = (const float*)d_in[1];
    const float* W_ih   = (const float*)d_in[2];
    const float* W_hh   = (const float*)d_in[3];
    const float* W_hh_b = (const float*)d_in[4];
    const float* b_h    = (const float*)d_in[5];
    const float* W      = (const float*)d_in[6];
    const float* bias   = (const float*)d_in[7];
    const int*   ctx    = (const int*)d_in[8];

    float* y  = (float*)d_out;                // (BATCH*SEQ,) = y[:,:,0]
    float* hs = y + (size_t)BATCH * SEQ;      // (BATCH, SEQ, HID) = out

    rnn_scan_kernel<<<BATCH, 512, 0, stream>>>(x, h0, W_ih, W_hh, W_hh_b,
                                               b_h, W, bias, ctx, y, hs);
}